// Round 1
// baseline (723.366 us; speedup 1.0000x reference)
//
#include <hip/hip_runtime.h>

#define TT 1024
#define BB 64
#define KK 16
#define HH 20
#define NCELL (KK * BB)   // 1024
#define CPW 3             // cells per 64-lane wave

__device__ __forceinline__ float sigm(float x) {
    return 1.0f / (1.0f + __expf(-x));
}

__device__ __forceinline__ float tanh_fast(float x) {
    // tanh(x) = 1 - 2/(exp(2x)+1); saturates correctly for |x| large.
    float e = __expf(2.0f * x);
    return 1.0f - 2.0f / (e + 1.0f);
}

// One wave per block; 3 cells per wave, 20 lanes per cell (lane j owns hidden unit j).
__global__ __launch_bounds__(64) void lstm_kernel(
    const float* __restrict__ inp,    // [B][T][K][3]
    const float* __restrict__ W_ih,   // [K][80][3]
    const float* __restrict__ W_hh,   // [K][80][20]
    const float* __restrict__ b_ih,   // [K][80]
    const float* __restrict__ b_hh,   // [K][80]
    const float* __restrict__ w,      // [K*B+1]
    const float* __restrict__ conv_w, // [21]
    const float* __restrict__ conv_b, // [1]
    float* __restrict__ y_ws)         // [1024] output y (pre-softmax, rows 1..1024)
{
    __shared__ float h_sh[CPW][HH];

    const int lane = threadIdx.x;
    const int lc   = lane / HH;        // local cell 0..2 (3 for lanes 60..63)
    const int j    = lane - lc * HH;   // hidden index 0..19
    const int cell = blockIdx.x * CPW + lc;
    const bool active = (lc < CPW) && (cell < NCELL);
    const int k = cell >> 6;           // cell = k*64 + b
    const int b = cell & 63;

    float Whh[4][HH];
    float Wih[4][3];
    float bias[4];
    float h_own = 0.0f, c_own = 0.0f;

    if (active) {
        #pragma unroll
        for (int g = 0; g < 4; ++g) {
            const int row = g * HH + j;
            const float* wr = W_hh + (k * 80 + row) * HH;
            #pragma unroll
            for (int hh = 0; hh < HH; ++hh) Whh[g][hh] = wr[hh];
            const float* wi = W_ih + (k * 80 + row) * 3;
            Wih[g][0] = wi[0]; Wih[g][1] = wi[1]; Wih[g][2] = wi[2];
            bias[g] = b_ih[k * 80 + row] + b_hh[k * 80 + row];
        }
        h_sh[lc][j] = 0.0f;
    }
    __syncthreads();

    // inp address for this cell: inp[((b*T + t)*K + k)*3 + i]
    const float* xbase = inp + (b * TT * KK + k) * 3;
    float x0 = 0.f, x1 = 0.f, x2 = 0.f;
    if (active) { x0 = xbase[0]; x1 = xbase[1]; x2 = xbase[2]; }

    for (int t = 0; t < TT; ++t) {
        // Prefetch next step's input (hides global latency under compute).
        float nx0 = 0.f, nx1 = 0.f, nx2 = 0.f;
        if (active && (t + 1 < TT)) {
            const float* q = xbase + (t + 1) * (KK * 3);
            nx0 = q[0]; nx1 = q[1]; nx2 = q[2];
        }

        if (active) {
            float a0 = bias[0] + Wih[0][0] * x0 + Wih[0][1] * x1 + Wih[0][2] * x2;
            float a1 = bias[1] + Wih[1][0] * x0 + Wih[1][1] * x1 + Wih[1][2] * x2;
            float a2 = bias[2] + Wih[2][0] * x0 + Wih[2][1] * x1 + Wih[2][2] * x2;
            float a3 = bias[3] + Wih[3][0] * x0 + Wih[3][1] * x1 + Wih[3][2] * x2;
            #pragma unroll
            for (int hh = 0; hh < HH; ++hh) {
                const float hv = h_sh[lc][hh];  // broadcast within cell
                a0 += Whh[0][hh] * hv;
                a1 += Whh[1][hh] * hv;
                a2 += Whh[2][hh] * hv;
                a3 += Whh[3][hh] * hv;
            }
            const float ig = sigm(a0);
            const float fg = sigm(a1);
            const float gg = tanh_fast(a2);
            const float og = sigm(a3);
            c_own = fg * c_own + ig * gg;
            h_own = og * tanh_fast(c_own);
        }
        __syncthreads();               // everyone done reading old h
        if (active) h_sh[lc][j] = h_own;
        __syncthreads();               // new h visible

        x0 = nx0; x1 = nx1; x2 = nx2;
    }

    // Epilogue: one lane per cell computes y = tanh(feat . conv_w + conv_b)
    if (active && j == 0) {
        float acc = conv_b[0];
        #pragma unroll
        for (int hh = 0; hh < HH; ++hh) acc += conv_w[hh] * h_sh[lc][hh];
        acc += conv_w[HH] * w[1 + cell];
        y_ws[cell] = tanh_fast(acc);
    }
}

// Softmax over [1, y_0 .. y_1023] -> out[1025]
__global__ __launch_bounds__(256) void softmax_kernel(
    const float* __restrict__ y_ws, float* __restrict__ out)
{
    __shared__ float red[4];
    const int tid = threadIdx.x;
    float vals[5];
    float local = 0.0f;
    #pragma unroll
    for (int it = 0; it < 5; ++it) {
        const int idx = tid + it * 256;
        if (idx < NCELL + 1) {
            const float y = (idx == 0) ? 1.0f : y_ws[idx - 1];
            const float e = __expf(y);
            vals[it] = e;
            local += e;
        } else {
            vals[it] = 0.0f;
        }
    }
    // wave (64-lane) reduction
    #pragma unroll
    for (int off = 32; off > 0; off >>= 1) local += __shfl_down(local, off, 64);
    if ((tid & 63) == 0) red[tid >> 6] = local;
    __syncthreads();
    const float total = red[0] + red[1] + red[2] + red[3];
    const float inv = 1.0f / total;
    #pragma unroll
    for (int it = 0; it < 5; ++it) {
        const int idx = tid + it * 256;
        if (idx < NCELL + 1) out[idx] = vals[it] * inv;
    }
}

extern "C" void kernel_launch(void* const* d_in, const int* in_sizes, int n_in,
                              void* d_out, int out_size, void* d_ws, size_t ws_size,
                              hipStream_t stream) {
    const float* inp    = (const float*)d_in[0];
    const float* w      = (const float*)d_in[1];
    const float* W_ih   = (const float*)d_in[2];
    const float* W_hh   = (const float*)d_in[3];
    const float* b_ih   = (const float*)d_in[4];
    const float* b_hh   = (const float*)d_in[5];
    const float* conv_w = (const float*)d_in[6];
    const float* conv_b = (const float*)d_in[7];
    float* out  = (float*)d_out;
    float* y_ws = (float*)d_ws;

    const int nblocks = (NCELL + CPW - 1) / CPW;  // 342
    lstm_kernel<<<nblocks, 64, 0, stream>>>(inp, W_ih, W_hh, b_ih, b_hh, w,
                                            conv_w, conv_b, y_ws);
    softmax_kernel<<<1, 256, 0, stream>>>(y_ws, out);
}

// Round 2
// 550.111 us; speedup vs baseline: 1.3149x; 1.3149x over previous
//
#include <hip/hip_runtime.h>

#define TT 1024
#define BB 64
#define KK 16
#define HH 20
#define NCELL (KK * BB)   // 1024
#define CPW 3             // cells per 64-lane wave

__device__ __forceinline__ float sigm(float x) {
    return 1.0f / (1.0f + __expf(-x));
}

__device__ __forceinline__ float tanh_fast(float x) {
    // tanh(x) = 1 - 2/(exp(2x)+1); saturates correctly for |x| large.
    float e = __expf(2.0f * x);
    return 1.0f - 2.0f / (e + 1.0f);
}

// One wave per block; 3 cells per wave, 20 lanes per cell (lane j owns hidden
// unit j: all four of j's gate rows live in lane j, so the only cross-lane
// traffic is the h broadcast — done with ds_bpermute (no LDS, no barriers).
__global__ __launch_bounds__(64) void lstm_kernel(
    const float* __restrict__ inp,    // [B][T][K][3]
    const float* __restrict__ W_ih,   // [K][80][3]
    const float* __restrict__ W_hh,   // [K][80][20]
    const float* __restrict__ b_ih,   // [K][80]
    const float* __restrict__ b_hh,   // [K][80]
    const float* __restrict__ w,      // [K*B+1]
    const float* __restrict__ conv_w, // [21]
    const float* __restrict__ conv_b, // [1]
    float* __restrict__ y_ws)         // [1024] pre-softmax y for rows 1..1024
{
    const int lane = threadIdx.x;
    const int lc   = lane / HH;        // local cell 0..2 (3 for lanes 60..63)
    const int j    = lane - lc * HH;   // hidden index 0..19
    const int cell = blockIdx.x * CPW + lc;
    const bool active = (lc < CPW) && (cell < NCELL);
    const int cellL = (cell < NCELL) ? cell : (NCELL - 1);  // clamped for loads
    const int k = cellL >> 6;          // cell = k*64 + b
    const int b = cellL & 63;
    const int lcBase = lc * HH;        // shuffle source base for this cell

    // Per-lane weights in registers, packed as (gate0,gate1)/(gate2,gate3).
    float2 W01[HH], W23[HH];
    float2 Wi01[3], Wi23[3];
    float2 bias01, bias23;
    {
        const int r0 = k * 80 + 0 * HH + j;
        const int r1 = k * 80 + 1 * HH + j;
        const int r2 = k * 80 + 2 * HH + j;
        const int r3 = k * 80 + 3 * HH + j;
        #pragma unroll
        for (int hh = 0; hh < HH; ++hh) {
            W01[hh] = make_float2(W_hh[r0 * HH + hh], W_hh[r1 * HH + hh]);
            W23[hh] = make_float2(W_hh[r2 * HH + hh], W_hh[r3 * HH + hh]);
        }
        #pragma unroll
        for (int i = 0; i < 3; ++i) {
            Wi01[i] = make_float2(W_ih[r0 * 3 + i], W_ih[r1 * 3 + i]);
            Wi23[i] = make_float2(W_ih[r2 * 3 + i], W_ih[r3 * 3 + i]);
        }
        bias01 = make_float2(b_ih[r0] + b_hh[r0], b_ih[r1] + b_hh[r1]);
        bias23 = make_float2(b_ih[r2] + b_hh[r2], b_ih[r3] + b_hh[r3]);
    }

    float h_own = 0.0f, c_own = 0.0f;

    // inp address for this cell: inp[((b*T + t)*K + k)*3 + i]
    const float* xbase = inp + (b * TT * KK + k) * 3;
    float x0 = xbase[0], x1 = xbase[1], x2 = xbase[2];

    for (int t = 0; t < TT; ++t) {
        // Prefetch next step's input (clamped; branchless).
        const float* q = xbase + ((t + 1 < TT) ? (t + 1) : (TT - 1)) * (KK * 3);
        const float nx0 = q[0], nx1 = q[1], nx2 = q[2];

        // Broadcast previous h across the cell's 20 lanes (ds_bpermute,
        // wave-synchronous — no barrier; same-source within group = broadcast).
        float hv[HH];
        #pragma unroll
        for (int hh = 0; hh < HH; ++hh) hv[hh] = __shfl(h_own, lcBase + hh, 64);

        float2 a01, a23;
        a01.x = bias01.x + Wi01[0].x * x0 + Wi01[1].x * x1 + Wi01[2].x * x2;
        a01.y = bias01.y + Wi01[0].y * x0 + Wi01[1].y * x1 + Wi01[2].y * x2;
        a23.x = bias23.x + Wi23[0].x * x0 + Wi23[1].x * x1 + Wi23[2].x * x2;
        a23.y = bias23.y + Wi23[0].y * x0 + Wi23[1].y * x1 + Wi23[2].y * x2;
        #pragma unroll
        for (int hh = 0; hh < HH; ++hh) {
            const float hvv = hv[hh];
            a01.x += W01[hh].x * hvv;
            a01.y += W01[hh].y * hvv;
            a23.x += W23[hh].x * hvv;
            a23.y += W23[hh].y * hvv;
        }
        const float ig = sigm(a01.x);
        const float fg = sigm(a01.y);
        const float gg = tanh_fast(a23.x);
        const float og = sigm(a23.y);
        c_own = fg * c_own + ig * gg;
        h_own = og * tanh_fast(c_own);

        x0 = nx0; x1 = nx1; x2 = nx2;
    }

    // Epilogue: broadcast final h, lane j==0 per cell computes
    // y = tanh(feat . conv_w + conv_b).
    float hv[HH];
    #pragma unroll
    for (int hh = 0; hh < HH; ++hh) hv[hh] = __shfl(h_own, lcBase + hh, 64);
    float acc = conv_b[0];
    #pragma unroll
    for (int hh = 0; hh < HH; ++hh) acc += conv_w[hh] * hv[hh];
    acc += conv_w[HH] * w[1 + cellL];
    if (active && j == 0) y_ws[cell] = tanh_fast(acc);
}

// Softmax over [1, y_0 .. y_1023] -> out[1025]
__global__ __launch_bounds__(256) void softmax_kernel(
    const float* __restrict__ y_ws, float* __restrict__ out)
{
    __shared__ float red[4];
    const int tid = threadIdx.x;
    float vals[5];
    float local = 0.0f;
    #pragma unroll
    for (int it = 0; it < 5; ++it) {
        const int idx = tid + it * 256;
        if (idx < NCELL + 1) {
            const float y = (idx == 0) ? 1.0f : y_ws[idx - 1];
            const float e = __expf(y);
            vals[it] = e;
            local += e;
        } else {
            vals[it] = 0.0f;
        }
    }
    // wave (64-lane) reduction
    #pragma unroll
    for (int off = 32; off > 0; off >>= 1) local += __shfl_down(local, off, 64);
    if ((tid & 63) == 0) red[tid >> 6] = local;
    __syncthreads();
    const float total = red[0] + red[1] + red[2] + red[3];
    const float inv = 1.0f / total;
    #pragma unroll
    for (int it = 0; it < 5; ++it) {
        const int idx = tid + it * 256;
        if (idx < NCELL + 1) out[idx] = vals[it] * inv;
    }
}

extern "C" void kernel_launch(void* const* d_in, const int* in_sizes, int n_in,
                              void* d_out, int out_size, void* d_ws, size_t ws_size,
                              hipStream_t stream) {
    const float* inp    = (const float*)d_in[0];
    const float* w      = (const float*)d_in[1];
    const float* W_ih   = (const float*)d_in[2];
    const float* W_hh   = (const float*)d_in[3];
    const float* b_ih   = (const float*)d_in[4];
    const float* b_hh   = (const float*)d_in[5];
    const float* conv_w = (const float*)d_in[6];
    const float* conv_b = (const float*)d_in[7];
    float* out  = (float*)d_out;
    float* y_ws = (float*)d_ws;

    const int nblocks = (NCELL + CPW - 1) / CPW;  // 342
    lstm_kernel<<<nblocks, 64, 0, stream>>>(inp, W_ih, W_hh, b_ih, b_hh, w,
                                            conv_w, conv_b, y_ws);
    softmax_kernel<<<1, 256, 0, stream>>>(y_ws, out);
}

// Round 3
// 506.672 us; speedup vs baseline: 1.4277x; 1.0857x over previous
//
#include <hip/hip_runtime.h>

#define TT 1024
#define KK 16
#define HH 20
#define NCELL 1024
#define CPW 3
#define PF 4   // input prefetch depth (steps)

typedef float f32x2 __attribute__((ext_vector_type(2)));

__device__ __forceinline__ f32x2 pk_fma(f32x2 a, f32x2 b, f32x2 c) {
    f32x2 d;
    asm("v_pk_fma_f32 %0, %1, %2, %3" : "=v"(d) : "v"(a), "v"(b), "v"(c));
    return d;
}

__device__ __forceinline__ float fast_rcp(float x) {
    return __builtin_amdgcn_rcpf(x);
}
__device__ __forceinline__ float sigm(float x) {
    return fast_rcp(1.0f + __expf(-x));
}
__device__ __forceinline__ float tanh_fast(float x) {
    // tanh(x) = 1 - 2/(exp(2x)+1)
    float e = __expf(2.0f * x);
    return 1.0f - 2.0f * fast_rcp(e + 1.0f);
}

struct F3 { float x, y, z; };

// One wave per block; 3 cells per wave, 20 lanes per cell (lane j owns hidden
// unit j's four gate rows). Cross-lane h broadcast via ds_bpermute (no LDS,
// no barriers). Gate dots via v_pk_fma_f32 with (even,odd) partial pairs.
__global__ __launch_bounds__(64) void lstm_kernel(
    const float* __restrict__ inp,    // [B][T][K][3]
    const float* __restrict__ W_ih,   // [K][80][3]
    const float* __restrict__ W_hh,   // [K][80][20]
    const float* __restrict__ b_ih,   // [K][80]
    const float* __restrict__ b_hh,   // [K][80]
    const float* __restrict__ w,      // [K*B+1]
    const float* __restrict__ conv_w, // [21]
    const float* __restrict__ conv_b, // [1]
    float* __restrict__ y_ws)         // [1024] pre-softmax y for rows 1..1024
{
    const int lane = threadIdx.x;
    const int lc   = lane / HH;        // local cell 0..2 (3 for lanes 60..63)
    const int j    = lane - lc * HH;   // hidden index 0..19
    const int cell = blockIdx.x * CPW + lc;
    const bool active = (lc < CPW) && (cell < NCELL);
    const int cellL = (cell < NCELL) ? cell : (NCELL - 1);
    const int k = cellL >> 6;
    const int b = cellL & 63;
    const int lcBase = lc * HH;        // lanes 60..63 read wrapped garbage; never stored

    // Per-lane weights in registers, packed (even hh, odd hh).
    f32x2 Wp0[10], Wp1[10], Wp2[10], Wp3[10];
    float Wi0[3], Wi1[3], Wi2[3], Wi3[3];
    float bias0, bias1, bias2, bias3;
    {
        const int r0 = k * 80 + 0 * HH + j;
        const int r1 = k * 80 + 1 * HH + j;
        const int r2 = k * 80 + 2 * HH + j;
        const int r3 = k * 80 + 3 * HH + j;
        #pragma unroll
        for (int m = 0; m < 10; ++m) {
            Wp0[m] = f32x2{W_hh[r0 * HH + 2 * m], W_hh[r0 * HH + 2 * m + 1]};
            Wp1[m] = f32x2{W_hh[r1 * HH + 2 * m], W_hh[r1 * HH + 2 * m + 1]};
            Wp2[m] = f32x2{W_hh[r2 * HH + 2 * m], W_hh[r2 * HH + 2 * m + 1]};
            Wp3[m] = f32x2{W_hh[r3 * HH + 2 * m], W_hh[r3 * HH + 2 * m + 1]};
        }
        #pragma unroll
        for (int i = 0; i < 3; ++i) {
            Wi0[i] = W_ih[r0 * 3 + i];
            Wi1[i] = W_ih[r1 * 3 + i];
            Wi2[i] = W_ih[r2 * 3 + i];
            Wi3[i] = W_ih[r3 * 3 + i];
        }
        bias0 = b_ih[r0] + b_hh[r0];
        bias1 = b_ih[r1] + b_hh[r1];
        bias2 = b_ih[r2] + b_hh[r2];
        bias3 = b_ih[r3] + b_hh[r3];
    }

    float h_own = 0.0f, c_own = 0.0f;

    // inp address for this cell: inp[((b*T + t)*K + k)*3 + i], stride 48 floats/t
    const float* xb = inp + (b * TT * KK + k) * 3;
    F3 p0{xb[0 * 48], xb[0 * 48 + 1], xb[0 * 48 + 2]};
    F3 p1{xb[1 * 48], xb[1 * 48 + 1], xb[1 * 48 + 2]};
    F3 p2{xb[2 * 48], xb[2 * 48 + 1], xb[2 * 48 + 2]};
    F3 p3{xb[3 * 48], xb[3 * 48 + 1], xb[3 * 48 + 2]};

    auto step = [&](F3& p, int t) {
        // 1) broadcast previous h across the cell's 20 lanes (pairs for pk_fma)
        f32x2 hv[10];
        #pragma unroll
        for (int m = 0; m < 10; ++m) {
            hv[m].x = __shfl(h_own, lcBase + 2 * m, 64);
            hv[m].y = __shfl(h_own, lcBase + 2 * m + 1, 64);
        }
        const float x0 = p.x, x1 = p.y, x2 = p.z;
        // 2) refill p for step t+PF (clamped; waitcnt deferred to use, 4 steps out)
        {
            int tn = t + PF; tn = (tn < TT) ? tn : (TT - 1);
            const float* q = xb + tn * (KK * 3);
            p.x = q[0]; p.y = q[1]; p.z = q[2];
        }
        // 3) x-projection + bias (independent of h; fills bpermute shadow)
        float e0 = bias0 + Wi0[0] * x0 + Wi0[1] * x1 + Wi0[2] * x2;
        float e1 = bias1 + Wi1[0] * x0 + Wi1[1] * x1 + Wi1[2] * x2;
        float e2 = bias2 + Wi2[0] * x0 + Wi2[1] * x1 + Wi2[2] * x2;
        float e3 = bias3 + Wi3[0] * x0 + Wi3[1] * x1 + Wi3[2] * x2;
        // 4) packed gate dots: acc = (even partial, odd partial)
        f32x2 a0{0.f, 0.f}, a1{0.f, 0.f}, a2{0.f, 0.f}, a3{0.f, 0.f};
        #pragma unroll
        for (int m = 0; m < 10; ++m) {
            a0 = pk_fma(Wp0[m], hv[m], a0);
            a1 = pk_fma(Wp1[m], hv[m], a1);
            a2 = pk_fma(Wp2[m], hv[m], a2);
            a3 = pk_fma(Wp3[m], hv[m], a3);
        }
        const float gi = e0 + (a0.x + a0.y);
        const float gf = e1 + (a1.x + a1.y);
        const float gz = e2 + (a2.x + a2.y);
        const float go = e3 + (a3.x + a3.y);
        // 5) nonlinearity + state update
        const float ig = sigm(gi);
        const float fg = sigm(gf);
        const float gt = tanh_fast(gz);
        const float og = sigm(go);
        c_own = fg * c_own + ig * gt;
        h_own = og * tanh_fast(c_own);
    };

    for (int tb = 0; tb < TT; tb += PF) {
        step(p0, tb + 0);
        step(p1, tb + 1);
        step(p2, tb + 2);
        step(p3, tb + 3);
    }

    // Epilogue: broadcast final h, lane j==0 per cell writes y = tanh(feat.conv_w + b)
    float hvf[HH];
    #pragma unroll
    for (int hh = 0; hh < HH; ++hh) hvf[hh] = __shfl(h_own, lcBase + hh, 64);
    float acc = conv_b[0];
    #pragma unroll
    for (int hh = 0; hh < HH; ++hh) acc += conv_w[hh] * hvf[hh];
    acc += conv_w[HH] * w[1 + cellL];
    if (active && j == 0) y_ws[cell] = tanh_fast(acc);
}

// Softmax over [1, y_0 .. y_1023] -> out[1025]
__global__ __launch_bounds__(256) void softmax_kernel(
    const float* __restrict__ y_ws, float* __restrict__ out)
{
    __shared__ float red[4];
    const int tid = threadIdx.x;
    float vals[5];
    float local = 0.0f;
    #pragma unroll
    for (int it = 0; it < 5; ++it) {
        const int idx = tid + it * 256;
        if (idx < NCELL + 1) {
            const float y = (idx == 0) ? 1.0f : y_ws[idx - 1];
            const float e = __expf(y);
            vals[it] = e;
            local += e;
        } else {
            vals[it] = 0.0f;
        }
    }
    #pragma unroll
    for (int off = 32; off > 0; off >>= 1) local += __shfl_down(local, off, 64);
    if ((tid & 63) == 0) red[tid >> 6] = local;
    __syncthreads();
    const float total = red[0] + red[1] + red[2] + red[3];
    const float inv = 1.0f / total;
    #pragma unroll
    for (int it = 0; it < 5; ++it) {
        const int idx = tid + it * 256;
        if (idx < NCELL + 1) out[idx] = vals[it] * inv;
    }
}

extern "C" void kernel_launch(void* const* d_in, const int* in_sizes, int n_in,
                              void* d_out, int out_size, void* d_ws, size_t ws_size,
                              hipStream_t stream) {
    const float* inp    = (const float*)d_in[0];
    const float* w      = (const float*)d_in[1];
    const float* W_ih   = (const float*)d_in[2];
    const float* W_hh   = (const float*)d_in[3];
    const float* b_ih   = (const float*)d_in[4];
    const float* b_hh   = (const float*)d_in[5];
    const float* conv_w = (const float*)d_in[6];
    const float* conv_b = (const float*)d_in[7];
    float* out  = (float*)d_out;
    float* y_ws = (float*)d_ws;

    const int nblocks = (NCELL + CPW - 1) / CPW;  // 342
    lstm_kernel<<<nblocks, 64, 0, stream>>>(inp, W_ih, W_hh, b_ih, b_hh, w,
                                            conv_w, conv_b, y_ws);
    softmax_kernel<<<1, 256, 0, stream>>>(y_ws, out);
}

// Round 4
// 297.195 us; speedup vs baseline: 2.4340x; 1.7048x over previous
//
#include <hip/hip_runtime.h>

#define TT 1024
#define KK 16
#define HH 20
#define NCELL 1024

typedef float f32x2 __attribute__((ext_vector_type(2)));

__device__ __forceinline__ f32x2 pk_fma(f32x2 a, f32x2 b, f32x2 c) {
    f32x2 d;
    asm("v_pk_fma_f32 %0, %1, %2, %3" : "=v"(d) : "v"(a), "v"(b), "v"(c));
    return d;
}

__device__ __forceinline__ float fast_rcp(float x) {
    return __builtin_amdgcn_rcpf(x);
}
__device__ __forceinline__ float sigm(float x) {
    return fast_rcp(1.0f + __expf(-x));
}
__device__ __forceinline__ float tanh_fast(float x) {
    float e = __expf(2.0f * x);
    return 1.0f - 2.0f * fast_rcp(e + 1.0f);
}

__device__ __forceinline__ float bcast(float v, int srclane) {
    return __int_as_float(__builtin_amdgcn_readlane(__float_as_int(v), srclane));
}

struct F3 { float x, y, z; };

// ONE cell per wave: lanes 0..19 own hidden units (lane j = unit j's four gate
// rows). The per-step h broadcast is 20 x v_readlane into SGPRs (VALU speed,
// no LDS pipe, no barriers). All control and input addresses are wave-uniform.
__global__ __launch_bounds__(64) void lstm_kernel(
    const float* __restrict__ inp,    // [B][T][K][3]
    const float* __restrict__ W_ih,   // [K][80][3]
    const float* __restrict__ W_hh,   // [K][80][20]
    const float* __restrict__ b_ih,   // [K][80]
    const float* __restrict__ b_hh,   // [K][80]
    const float* __restrict__ w,      // [K*B+1]
    const float* __restrict__ conv_w, // [21]
    const float* __restrict__ conv_b, // [1]
    float* __restrict__ y_ws)         // [1024] pre-softmax y for rows 1..1024
{
    const int lane = threadIdx.x;
    const int cell = blockIdx.x;           // 0..1023
    const int k = cell >> 6;
    const int b = cell & 63;
    const int j = (lane < HH) ? lane : (HH - 1);  // lanes 20..63 shadow unit 19

    // Per-lane weights in registers, packed (even hh, odd hh) for v_pk_fma.
    f32x2 Wp0[10], Wp1[10], Wp2[10], Wp3[10];
    float Wi0[3], Wi1[3], Wi2[3], Wi3[3];
    float bias0, bias1, bias2, bias3;
    {
        const int r0 = k * 80 + 0 * HH + j;
        const int r1 = k * 80 + 1 * HH + j;
        const int r2 = k * 80 + 2 * HH + j;
        const int r3 = k * 80 + 3 * HH + j;
        #pragma unroll
        for (int m = 0; m < 10; ++m) {
            Wp0[m] = f32x2{W_hh[r0 * HH + 2 * m], W_hh[r0 * HH + 2 * m + 1]};
            Wp1[m] = f32x2{W_hh[r1 * HH + 2 * m], W_hh[r1 * HH + 2 * m + 1]};
            Wp2[m] = f32x2{W_hh[r2 * HH + 2 * m], W_hh[r2 * HH + 2 * m + 1]};
            Wp3[m] = f32x2{W_hh[r3 * HH + 2 * m], W_hh[r3 * HH + 2 * m + 1]};
        }
        #pragma unroll
        for (int i = 0; i < 3; ++i) {
            Wi0[i] = W_ih[r0 * 3 + i];
            Wi1[i] = W_ih[r1 * 3 + i];
            Wi2[i] = W_ih[r2 * 3 + i];
            Wi3[i] = W_ih[r3 * 3 + i];
        }
        bias0 = b_ih[r0] + b_hh[r0];
        bias1 = b_ih[r1] + b_hh[r1];
        bias2 = b_ih[r2] + b_hh[r2];
        bias3 = b_ih[r3] + b_hh[r3];
    }

    float h_own = 0.0f, c_own = 0.0f;

    // Wave-uniform input base: inp[((b*T + t)*K + k)*3], stride 48 floats/t.
    const float* xb = inp + (b * TT * KK + k) * 3;
    F3 p0{xb[0 * 48], xb[0 * 48 + 1], xb[0 * 48 + 2]};
    F3 p1{xb[1 * 48], xb[1 * 48 + 1], xb[1 * 48 + 2]};
    F3 p2{xb[2 * 48], xb[2 * 48 + 1], xb[2 * 48 + 2]};
    F3 p3{xb[3 * 48], xb[3 * 48 + 1], xb[3 * 48 + 2]};

    auto step = [&](F3& p, int t) {
        // 1) h broadcast: 20 readlanes -> uniform pairs (VALU, no LDS pipe)
        f32x2 hp[10];
        #pragma unroll
        for (int m = 0; m < 10; ++m) {
            const float lo = bcast(h_own, 2 * m);
            const float hi = bcast(h_own, 2 * m + 1);
            hp[m] = f32x2{lo, hi};
        }
        const float x0 = p.x, x1 = p.y, x2 = p.z;
        // 2) refill p for step t+4 (uniform address; latency spans 4 steps)
        {
            int tn = t + 4; tn = (tn < TT) ? tn : (TT - 1);
            const float* q = xb + tn * (KK * 3);
            p.x = q[0]; p.y = q[1]; p.z = q[2];
        }
        // 3) x-projection + bias (x uniform -> SGPR operand in FMAs)
        const float e0 = bias0 + Wi0[0] * x0 + Wi0[1] * x1 + Wi0[2] * x2;
        const float e1 = bias1 + Wi1[0] * x0 + Wi1[1] * x1 + Wi1[2] * x2;
        const float e2 = bias2 + Wi2[0] * x0 + Wi2[1] * x1 + Wi2[2] * x2;
        const float e3 = bias3 + Wi3[0] * x0 + Wi3[1] * x1 + Wi3[2] * x2;
        // 4) packed gate dots
        f32x2 a0{e0, 0.f}, a1{e1, 0.f}, a2{e2, 0.f}, a3{e3, 0.f};
        #pragma unroll
        for (int m = 0; m < 10; ++m) {
            a0 = pk_fma(Wp0[m], hp[m], a0);
            a1 = pk_fma(Wp1[m], hp[m], a1);
            a2 = pk_fma(Wp2[m], hp[m], a2);
            a3 = pk_fma(Wp3[m], hp[m], a3);
        }
        const float gi = a0.x + a0.y;
        const float gf = a1.x + a1.y;
        const float gz = a2.x + a2.y;
        const float go = a3.x + a3.y;
        // 5) nonlinearity + state update
        const float ig = sigm(gi);
        const float fg = sigm(gf);
        const float gt = tanh_fast(gz);
        const float og = sigm(go);
        c_own = fg * c_own + ig * gt;
        h_own = og * tanh_fast(c_own);
    };

    for (int tb = 0; tb < TT; tb += 4) {
        step(p0, tb + 0);
        step(p1, tb + 1);
        step(p2, tb + 2);
        step(p3, tb + 3);
    }

    // Epilogue: final h via readlane (uniform), y = tanh(feat . conv_w + conv_b)
    float acc = conv_b[0];
    #pragma unroll
    for (int hh = 0; hh < HH; ++hh) acc += conv_w[hh] * bcast(h_own, hh);
    acc += conv_w[HH] * w[1 + cell];
    if (lane == 0) y_ws[cell] = tanh_fast(acc);
}

// Softmax over [1, y_0 .. y_1023] -> out[1025]
__global__ __launch_bounds__(256) void softmax_kernel(
    const float* __restrict__ y_ws, float* __restrict__ out)
{
    __shared__ float red[4];
    const int tid = threadIdx.x;
    float vals[5];
    float local = 0.0f;
    #pragma unroll
    for (int it = 0; it < 5; ++it) {
        const int idx = tid + it * 256;
        if (idx < NCELL + 1) {
            const float y = (idx == 0) ? 1.0f : y_ws[idx - 1];
            const float e = __expf(y);
            vals[it] = e;
            local += e;
        } else {
            vals[it] = 0.0f;
        }
    }
    #pragma unroll
    for (int off = 32; off > 0; off >>= 1) local += __shfl_down(local, off, 64);
    if ((tid & 63) == 0) red[tid >> 6] = local;
    __syncthreads();
    const float total = red[0] + red[1] + red[2] + red[3];
    const float inv = 1.0f / total;
    #pragma unroll
    for (int it = 0; it < 5; ++it) {
        const int idx = tid + it * 256;
        if (idx < NCELL + 1) out[idx] = vals[it] * inv;
    }
}

extern "C" void kernel_launch(void* const* d_in, const int* in_sizes, int n_in,
                              void* d_out, int out_size, void* d_ws, size_t ws_size,
                              hipStream_t stream) {
    const float* inp    = (const float*)d_in[0];
    const float* w      = (const float*)d_in[1];
    const float* W_ih   = (const float*)d_in[2];
    const float* W_hh   = (const float*)d_in[3];
    const float* b_ih   = (const float*)d_in[4];
    const float* b_hh   = (const float*)d_in[5];
    const float* conv_w = (const float*)d_in[6];
    const float* conv_b = (const float*)d_in[7];
    float* out  = (float*)d_out;
    float* y_ws = (float*)d_ws;

    lstm_kernel<<<NCELL, 64, 0, stream>>>(inp, W_ih, W_hh, b_ih, b_hh, w,
                                          conv_w, conv_b, y_ws);
    softmax_kernel<<<1, 256, 0, stream>>>(y_ws, out);
}